// Round 3
// baseline (308.952 us; speedup 1.0000x reference)
//
#include <hip/hip_runtime.h>
#include <hip/hip_bf16.h>
#include <math.h>

// Attention_29953101922931: B=8,S=1024,H=16,D=64,W=1024
// R5: qkv rewritten as the 256x256 8-phase-style template (plain HIP port):
//     one fused GEMM M=8192 x N=3072 (Q|K|V via concatenated Wt) x K=1024,
//     BK=64 in two k-halves, 512 thr / 8 waves (2M x 4N), 128KB LDS dbuf,
//     counted vmcnt(4) (never 0 in main loop), raw s_barrier (no vmcnt(0)
//     drain), T2 seg-XOR swizzle on global source + LDS read (linear dest
//     for global_load_lds), T5 setprio around each 16-MFMA cluster.
//     cast2/transpose/attn unchanged from R4.

#define B_ 8
#define S_ 1024
#define H_ 16
#define D_ 64
#define W_ 1024

typedef __bf16 bf16x8 __attribute__((ext_vector_type(8)));
typedef float f32x4 __attribute__((ext_vector_type(4)));
typedef unsigned short ushort_t;

#define MFMA16(a, b, c) __builtin_amdgcn_mfma_f32_16x16x32_bf16((a), (b), (c), 0, 0, 0)

__device__ inline ushort_t f2bf(float f) {  // RTNE fp32->bf16
    unsigned int u = __float_as_uint(f);
    u += 0x7fff + ((u >> 16) & 1);
    return (ushort_t)(u >> 16);
}

__device__ inline ushort_t f2bf_rhu(float f) {  // round-half-up, 2 VALU ops (p>=0)
    return (ushort_t)((__float_as_uint(f) + 0x8000u) >> 16);
}

__device__ inline void async16(const void* g, void* l) {
    __builtin_amdgcn_global_load_lds((const __attribute__((address_space(1))) void*)g,
                                     (__attribute__((address_space(3))) void*)l, 16, 0, 0);
}

#define RAW_BARRIER() asm volatile("s_barrier" ::: "memory")
#define VMCNT(n) asm volatile("s_waitcnt vmcnt(" #n ")" ::: "memory")

// Both input casts in one dispatch: grid (n4/256, 2)
__global__ __launch_bounds__(256) void cast2_bf16(const float* __restrict__ a,
                                                  const float* __restrict__ b,
                                                  ushort_t* __restrict__ da,
                                                  ushort_t* __restrict__ db, int n4) {
    int i = blockIdx.x * 256 + threadIdx.x;
    if (i >= n4) return;
    const float* src = blockIdx.y ? b : a;
    ushort_t* dst = blockIdx.y ? db : da;
    float4 v = ((const float4*)src)[i];
    ushort4 o;
    o.x = f2bf(v.x); o.y = f2bf(v.y); o.z = f2bf(v.z); o.w = f2bf(v.w);
    ((ushort4*)dst)[i] = o;
}

// Wt[z][n][k] = W_z[k][n], cast to bf16. block (32,8), grid (32,32,3)
__global__ __launch_bounds__(256) void transpose_cast(const float* __restrict__ Wq,
                                                      const float* __restrict__ Wk,
                                                      const float* __restrict__ Wv,
                                                      ushort_t* __restrict__ Wt) {
    __shared__ float tile[32][33];
    int z = blockIdx.z;
    const float* src = (z == 0) ? Wq : (z == 1 ? Wk : Wv);
    ushort_t* dst = Wt + (size_t)z * W_ * W_;
    int tx = threadIdx.x, ty = threadIdx.y;
    int x = blockIdx.x * 32 + tx;
#pragma unroll
    for (int jj = 0; jj < 4; jj++) {
        int y = blockIdx.y * 32 + ty + jj * 8;
        tile[ty + jj * 8][tx] = src[(size_t)y * W_ + x];
    }
    __syncthreads();
    int x2 = blockIdx.y * 32 + tx;
#pragma unroll
    for (int jj = 0; jj < 4; jj++) {
        int y2 = blockIdx.x * 32 + ty + jj * 8;
        dst[(size_t)y2 * W_ + x2] = f2bf(tile[tx][ty + jj * 8]);
    }
}

// Fused QKV GEMM, 256x256 tile, 8-phase-style pipeline.
// C[8192][3072] = A x Wt^T(+flat [3072][1024]); A = fromB (n<1024) else toB.
// Grid: 384 blocks (32 mTiles x 12 nTiles), XCD remap: xcd=bid&7, j=bid>>3,
// mTile=xcd*4+(j&3), nTile=j>>2. 512 threads = 8 waves (wm=w>>2, wn=w&3);
// wave output 128x64 = acc[8][4] 16x16 frags. BK=64 as two 256x32 k-halves.
// LDS [2 buf][2 khalf][256][32] per operand = 64KB each, 128KB total.
// Swizzle: 16B seg s stored at s^((row>>1)&3) via pre-swizzled GLOBAL source
// (LDS dest linear, rule both-sides-or-neither); read seg = qd^((ln>>1)&3).
// Ledger (per-wave vm instrs, halves=2 instrs, issue order Ak0,Bk0,Ak1,Bk1):
//   P1: vmcnt(4) [Ak0,Bk0 landed] BAR; issue next Ak0; kf0 x j{0,1} MFMA; BAR
//   P2: issue next Bk0; kf0 x j{2,3}; BAR
//   P3: vmcnt(4) [Ak1,Bk1] (last tile: 0) BAR; issue next Ak1; kf1 x j{0,1}; BAR
//   P4: issue next Bk1; kf1 x j{2,3}; BAR     (outstanding: 8 max, >=4 floor)
__global__ __launch_bounds__(512, 2) void qkv_gemm8(const ushort_t* __restrict__ fromB,
                                                    const ushort_t* __restrict__ toB,
                                                    const ushort_t* __restrict__ Wt,
                                                    const float* __restrict__ bq,
                                                    const float* __restrict__ bk,
                                                    const float* __restrict__ bv,
                                                    ushort_t* __restrict__ Qd,
                                                    ushort_t* __restrict__ Kd,
                                                    ushort_t* __restrict__ Vt) {
    __shared__ __attribute__((aligned(16))) ushort_t As[2 * 2 * 8192];
    __shared__ __attribute__((aligned(16))) ushort_t Bs[2 * 2 * 8192];

    int bid = blockIdx.x;
    int xcd = bid & 7, jb = bid >> 3;      // jb 0..47
    int mTile = xcd * 4 + (jb & 3);        // 0..31
    int nTile = jb >> 2;                   // 0..11
    int mBase = mTile << 8, nBase = nTile << 8;
    int z = nTile >> 2;                    // 0=Q 1=K 2=V
    const ushort_t* A = (z == 0) ? fromB : toB;
    const float* bias = (z == 0) ? bq : (z == 1 ? bk : bv);
    ushort_t* dst = (z == 0) ? Qd : (z == 1 ? Kd : Vt);
    float qscale = (z == 0) ? 0.18033688011111773f : 1.0f;  // (1/8)*log2(e)

    int t = threadIdx.x;
    int lane = t & 63, w = t >> 6;
    int wm = w >> 2, wn = w & 3;
    int ln = lane & 15, qd = lane >> 4;
    int wb = t & ~63;
    int fs = (qd ^ ((ln >> 1) & 3)) << 3;  // swizzled frag seg (elements)

    // staging constants: instr l covers flat idx = l*512+t; row=idx>>2 (0..255
    // over l), stored seg = idx&3, global seg = (idx&3)^((idx>>3)&3) (l-invariant)
    int rowL0 = t >> 2;
    int sG = ((t & 3) ^ ((t >> 3) & 3)) << 3;
    const ushort_t* pA0 = A + (size_t)(mBase + rowL0) * W_ + sG;
    const ushort_t* pA1 = A + (size_t)(mBase + 128 + rowL0) * W_ + sG;
    const ushort_t* pB0 = Wt + (size_t)(nBase + rowL0) * W_ + sG;
    const ushort_t* pB1 = Wt + (size_t)(nBase + 128 + rowL0) * W_ + sG;
    int d0 = wb * 8;           // wave-uniform LDS elem offset, instr l=0
    int d1 = (512 + wb) * 8;   // instr l=1

    f32x4 zero = {0.f, 0.f, 0.f, 0.f};
    f32x4 acc[8][4];
#pragma unroll
    for (int i = 0; i < 8; i++)
#pragma unroll
        for (int jj = 0; jj < 4; jj++) acc[i][jj] = zero;

    // prologue: tile 0 -> buf 0, order Ak0,Bk0,Ak1,Bk1
    async16(pA0, As + d0); async16(pA1, As + d1);
    async16(pB0, Bs + d0); async16(pB1, Bs + d1);
    async16(pA0 + 32, As + 8192 + d0); async16(pA1 + 32, As + 8192 + d1);
    async16(pB0 + 32, Bs + 8192 + d0); async16(pB1 + 32, Bs + 8192 + d1);

    int aw = wm * 128 + ln;  // A frag base row (add i*16)
    int bw = wn * 64 + ln;   // B frag base row (add j*16)

    for (int kt = 0; kt < 16; ++kt) {
        int buf = kt & 1, nb = buf ^ 1;
        int hb0 = (buf << 14);            // buf*2*8192 (khalf 0)
        int hb1 = hb0 + 8192;             // khalf 1
        int nh0 = (nb << 14);
        int nh1 = nh0 + 8192;
        int nOff = (kt + 1) << 6;         // next tile global k (elements)
        bool pf = kt < 15;

        bf16x8 af[8], b0, b1, b2, b3;

        // ---- P1: kf0, j{0,1}
        VMCNT(4);
        RAW_BARRIER();
        if (pf) { async16(pA0 + nOff, As + nh0 + d0); async16(pA1 + nOff, As + nh0 + d1); }
#pragma unroll
        for (int i = 0; i < 8; i++) af[i] = *(const bf16x8*)(As + hb0 + (aw + i * 16) * 32 + fs);
        b0 = *(const bf16x8*)(Bs + hb0 + bw * 32 + fs);
        b1 = *(const bf16x8*)(Bs + hb0 + (bw + 16) * 32 + fs);
        __builtin_amdgcn_s_setprio(1);
#pragma unroll
        for (int i = 0; i < 8; i++) {
            acc[i][0] = MFMA16(af[i], b0, acc[i][0]);
            acc[i][1] = MFMA16(af[i], b1, acc[i][1]);
        }
        __builtin_amdgcn_s_setprio(0);
        RAW_BARRIER();

        // ---- P2: kf0, j{2,3}
        if (pf) { async16(pB0 + nOff, Bs + nh0 + d0); async16(pB1 + nOff, Bs + nh0 + d1); }
        b2 = *(const bf16x8*)(Bs + hb0 + (bw + 32) * 32 + fs);
        b3 = *(const bf16x8*)(Bs + hb0 + (bw + 48) * 32 + fs);
        __builtin_amdgcn_s_setprio(1);
#pragma unroll
        for (int i = 0; i < 8; i++) {
            acc[i][2] = MFMA16(af[i], b2, acc[i][2]);
            acc[i][3] = MFMA16(af[i], b3, acc[i][3]);
        }
        __builtin_amdgcn_s_setprio(0);
        RAW_BARRIER();

        // ---- P3: kf1, j{0,1}
        if (pf) { VMCNT(4); } else { VMCNT(0); }
        RAW_BARRIER();
        if (pf) { async16(pA0 + nOff + 32, As + nh1 + d0); async16(pA1 + nOff + 32, As + nh1 + d1); }
#pragma unroll
        for (int i = 0; i < 8; i++) af[i] = *(const bf16x8*)(As + hb1 + (aw + i * 16) * 32 + fs);
        b0 = *(const bf16x8*)(Bs + hb1 + bw * 32 + fs);
        b1 = *(const bf16x8*)(Bs + hb1 + (bw + 16) * 32 + fs);
        __builtin_amdgcn_s_setprio(1);
#pragma unroll
        for (int i = 0; i < 8; i++) {
            acc[i][0] = MFMA16(af[i], b0, acc[i][0]);
            acc[i][1] = MFMA16(af[i], b1, acc[i][1]);
        }
        __builtin_amdgcn_s_setprio(0);
        RAW_BARRIER();

        // ---- P4: kf1, j{2,3}
        if (pf) { async16(pB0 + nOff + 32, Bs + nh1 + d0); async16(pB1 + nOff + 32, Bs + nh1 + d1); }
        b2 = *(const bf16x8*)(Bs + hb1 + (bw + 32) * 32 + fs);
        b3 = *(const bf16x8*)(Bs + hb1 + (bw + 48) * 32 + fs);
        __builtin_amdgcn_s_setprio(1);
#pragma unroll
        for (int i = 0; i < 8; i++) {
            acc[i][2] = MFMA16(af[i], b2, acc[i][2]);
            acc[i][3] = MFMA16(af[i], b3, acc[i][3]);
        }
        __builtin_amdgcn_s_setprio(0);
        RAW_BARRIER();
    }

    // epilogue: bias + (Q-scale) + scatter to [B,H,S,D] (Q,K) / [B,H,D,S] (V)
#pragma unroll
    for (int jj = 0; jj < 4; jj++) {
        int n = nBase + wn * 64 + jj * 16 + ln;
        int nn = n & 1023;
        float bb = bias[nn];
        int h = nn >> 6, d = nn & 63;
#pragma unroll
        for (int i = 0; i < 8; i++) {
            int mrow = mBase + wm * 128 + i * 16 + qd * 4;
#pragma unroll
            for (int r = 0; r < 4; r++) {
                int m = mrow + r;
                int b = m >> 10, s = m & 1023;
                float v = (acc[i][jj][r] + bb) * qscale;
                size_t idx;
                if (z < 2) idx = ((size_t)(b * H_ + h) * S_ + s) * D_ + d;
                else       idx = ((size_t)(b * H_ + h) * D_ + d) * S_ + s;
                dst[idx] = f2bf(v);
            }
        }
    }
}

// Flash attention v2. grid (S/128, B*H), block 256 (4 waves x 32 queries).
// Q,K: [B,H,S,D] bf16 (Q pre-scaled by 0.125*log2e); V: [B,H,D,S] bf16.
// K/V chunks (64 keys) staged in LDS via global_load_lds, double-buffered,
// XOR-swizzle (seg ^= row&7) for bank balance. No max-subtraction softmax.
__global__ __launch_bounds__(256, 3) void attn(const ushort_t* __restrict__ Qd,
                                               const ushort_t* __restrict__ Kd,
                                               const ushort_t* __restrict__ Vt,
                                               float* __restrict__ out) {
    __shared__ __attribute__((aligned(16))) ushort_t Ks[2][4096];   // [buf][64 keys x 64 d]
    __shared__ __attribute__((aligned(16))) ushort_t Vs[2][4096];   // [buf][64 d x 64 keys]
    __shared__ __attribute__((aligned(16))) ushort_t Plds[4][32][72];

    int bh = blockIdx.y;
    int t = threadIdx.x, w = t >> 6, lane = t & 63;
    int ln = lane & 15, qd = lane >> 4;
    int qbase = blockIdx.x * 128 + w * 32;
    const ushort_t* Qb = Qd + (size_t)bh * S_ * D_;
    const ushort_t* Kb = Kd + (size_t)bh * S_ * D_;
    const ushort_t* Vb = Vt + (size_t)bh * D_ * S_;

    // Q A-frags: 2 m-tiles x 2 k-halves (lane ln holds row, qd*8 k-offset)
    bf16x8 qf[2][2];
#pragma unroll
    for (int i = 0; i < 2; i++) {
        const ushort_t* qp = Qb + (size_t)(qbase + i * 16 + ln) * D_ + qd * 8;
        qf[i][0] = *(const bf16x8*)qp;
        qf[i][1] = *(const bf16x8*)(qp + 32);
    }

    // staging per-lane constants (8 rows x 64 elem per 1KB async16 block)
    int l8 = lane >> 3, s8 = lane & 7;
    int stgOff = (s8 ^ l8) << 3;  // swizzled 8-elem segment
    const ushort_t* kg = Kb + (size_t)(w * 16 + l8) * D_ + stgOff;
    const ushort_t* vg = Vb + (size_t)(w * 16 + l8) * S_ + stgOff;
    // frag-read per-lane constant: row ln (mod 16), seg qd swizzled by row&7
    int kOff = ln * 64 + ((qd ^ (ln & 7)) << 3);

    float rs[2][4];
    f32x4 zero = {0.f, 0.f, 0.f, 0.f};
    f32x4 accO[2][4];
#pragma unroll
    for (int i = 0; i < 2; i++) {
        rs[i][0] = rs[i][1] = rs[i][2] = rs[i][3] = 0.f;
#pragma unroll
        for (int jd = 0; jd < 4; jd++) accO[i][jd] = zero;
    }

    // preload chunk 0 into buf 0 (4 async16 per wave: 2 K-blocks + 2 V-blocks)
    async16(kg, &Ks[0][w * 1024]);
    async16(kg + 8 * D_, &Ks[0][w * 1024 + 512]);
    async16(vg, &Vs[0][w * 1024]);
    async16(vg + 8 * S_, &Vs[0][w * 1024 + 512]);

    for (int c = 0; c < 16; ++c) {
        int buf = c & 1;
        __builtin_amdgcn_s_waitcnt(0x0F70);  // vmcnt(0): chunk c staged
        __syncthreads();                     // all waves: staged + done reading buf^1
        if (c + 1 < 16) {                    // prefetch c+1; lands during compute(c)
            int kc = (c + 1) * 64;
            async16(kg + (size_t)kc * D_, &Ks[buf ^ 1][w * 1024]);
            async16(kg + (size_t)kc * D_ + 8 * D_, &Ks[buf ^ 1][w * 1024 + 512]);
            async16(vg + kc, &Vs[buf ^ 1][w * 1024]);
            async16(vg + kc + 8 * S_, &Vs[buf ^ 1][w * 1024 + 512]);
        }

        // S = Q K^T
        f32x4 sc[2][4];
#pragma unroll
        for (int i = 0; i < 2; i++)
#pragma unroll
            for (int j = 0; j < 4; j++) sc[i][j] = zero;
        __builtin_amdgcn_s_setprio(1);
#pragma unroll
        for (int j = 0; j < 4; j++) {
            bf16x8 k0 = *(const bf16x8*)&Ks[buf][j * 1024 + kOff];
            bf16x8 k1 = *(const bf16x8*)&Ks[buf][(j * 1024 + kOff) ^ 32];
#pragma unroll
            for (int i = 0; i < 2; i++) {
                sc[i][j] = MFMA16(qf[i][0], k0, sc[i][j]);
                sc[i][j] = MFMA16(qf[i][1], k1, sc[i][j]);
            }
        }
        __builtin_amdgcn_s_setprio(0);
        // p = exp2(score) (log2e pre-folded into Q); accumulate row sums
#pragma unroll
        for (int i = 0; i < 2; i++)
#pragma unroll
            for (int j = 0; j < 4; j++)
#pragma unroll
                for (int r = 0; r < 4; r++) {
                    float p = exp2f(sc[i][j][r]);
                    rs[i][r] += p;
                    Plds[w][i * 16 + qd * 4 + r][j * 16 + ln] = f2bf_rhu(p);
                }
        // C-layout -> A-layout via per-wave LDS slice (same-wave DS order: no barrier)
        bf16x8 pf[2][2];
#pragma unroll
        for (int i = 0; i < 2; i++) {
            pf[i][0] = *(const bf16x8*)&Plds[w][i * 16 + ln][qd * 8];
            pf[i][1] = *(const bf16x8*)&Plds[w][i * 16 + ln][32 + qd * 8];
        }
        // O += P V
        __builtin_amdgcn_s_setprio(1);
#pragma unroll
        for (int jd = 0; jd < 4; jd++) {
            bf16x8 v0 = *(const bf16x8*)&Vs[buf][jd * 1024 + kOff];
            bf16x8 v1 = *(const bf16x8*)&Vs[buf][(jd * 1024 + kOff) ^ 32];
#pragma unroll
            for (int i = 0; i < 2; i++) {
                accO[i][jd] = MFMA16(pf[i][0], v0, accO[i][jd]);
                accO[i][jd] = MFMA16(pf[i][1], v1, accO[i][jd]);
            }
        }
        __builtin_amdgcn_s_setprio(0);
    }

    int b = bh >> 4, h = bh & 15;
#pragma unroll
    for (int i = 0; i < 2; i++)
#pragma unroll
        for (int r = 0; r < 4; r++) {
            float s = rs[i][r];
            s += __shfl_xor(s, 1);
            s += __shfl_xor(s, 2);
            s += __shfl_xor(s, 4);
            s += __shfl_xor(s, 8);
            float inv = 1.f / s;
            int q = qbase + i * 16 + qd * 4 + r;
            float* op = out + ((size_t)(b * S_ + q) * H_ + h) * D_;
#pragma unroll
            for (int jd = 0; jd < 4; jd++) op[jd * 16 + ln] = accO[i][jd][r] * inv;
        }
}

extern "C" void kernel_launch(void* const* d_in, const int* in_sizes, int n_in,
                              void* d_out, int out_size, void* d_ws, size_t ws_size,
                              hipStream_t stream) {
    const float* from = (const float*)d_in[0];
    const float* to_  = (const float*)d_in[1];
    const float* Wq = (const float*)d_in[2];
    const float* bq = (const float*)d_in[3];
    const float* Wk = (const float*)d_in[4];
    const float* bk = (const float*)d_in[5];
    const float* Wv = (const float*)d_in[6];
    const float* bv = (const float*)d_in[7];
    float* out = (float*)d_out;

    const size_t NTOK = (size_t)B_ * S_ * W_;  // 8388608
    ushort_t* ws = (ushort_t*)d_ws;
    ushort_t* fromB = ws;
    ushort_t* toB = fromB + NTOK;
    ushort_t* Wt = toB + NTOK;
    ushort_t* Qd = Wt + (size_t)3 * W_ * W_;
    ushort_t* Kd = Qd + NTOK;
    ushort_t* Vt = Kd + NTOK;

    int n4 = (int)(NTOK / 4);
    cast2_bf16<<<dim3(n4 / 256, 2), dim3(256), 0, stream>>>(from, to_, fromB, toB, n4);
    transpose_cast<<<dim3(32, 32, 3), dim3(32, 8), 0, stream>>>(Wq, Wk, Wv, Wt);
    qkv_gemm8<<<dim3(384), dim3(512), 0, stream>>>(fromB, toB, Wt, bq, bk, bv, Qd, Kd, Vt);
    attn<<<dim3(8, 128), dim3(256), 0, stream>>>(Qd, Kd, Vt, out);
}

// Round 5
// 272.996 us; speedup vs baseline: 1.1317x; 1.1317x over previous
//
#include <hip/hip_runtime.h>
#include <hip/hip_bf16.h>
#include <math.h>

// Attention_29953101922931: B=8,S=1024,H=16,D=64,W=1024
// R7: qkv = R4 loop + R5-proven seg-XOR swizzle (kept from R6; R6's failure
//     isolated to the tr16 attn path — swizzle math identical to R5's pass).
//     attn: swapped QK^T — mfma(K,Q) instead of mfma(Q,K). A/B frag lane maps
//     coincide, so operand swap is free; C-frag becomes P[key][q] with the 4
//     per-reg values = CONSECUTIVE KEYS -> P-store is 8 aligned ds_write_b64
//     (was 32 ds_write_u16). Read side = R4's proven b128 pattern. Row-sum:
//     scalar per i, reduced over qd lanes (shfl_xor 16,32), redistributed to
//     output lanes via __shfl(inv, qd*4+r). No tr16, no new instructions.

#define B_ 8
#define S_ 1024
#define H_ 16
#define D_ 64
#define W_ 1024

typedef __bf16 bf16x8 __attribute__((ext_vector_type(8)));
typedef float f32x4 __attribute__((ext_vector_type(4)));
typedef unsigned short ushort_t;

#define MFMA16(a, b, c) __builtin_amdgcn_mfma_f32_16x16x32_bf16((a), (b), (c), 0, 0, 0)

__device__ inline ushort_t f2bf(float f) {  // RTNE fp32->bf16
    unsigned int u = __float_as_uint(f);
    u += 0x7fff + ((u >> 16) & 1);
    return (ushort_t)(u >> 16);
}

__device__ inline unsigned f2bf_rhu_u(float f) {  // round-half-up bf16 bits (p>=0)
    return (__float_as_uint(f) + 0x8000u) >> 16;
}

__device__ inline void async16(const void* g, void* l) {
    __builtin_amdgcn_global_load_lds((const __attribute__((address_space(1))) void*)g,
                                     (__attribute__((address_space(3))) void*)l, 16, 0, 0);
}

// Both input casts in one dispatch: grid (n4/256, 2)
__global__ __launch_bounds__(256) void cast2_bf16(const float* __restrict__ a,
                                                  const float* __restrict__ b,
                                                  ushort_t* __restrict__ da,
                                                  ushort_t* __restrict__ db, int n4) {
    int i = blockIdx.x * 256 + threadIdx.x;
    if (i >= n4) return;
    const float* src = blockIdx.y ? b : a;
    ushort_t* dst = blockIdx.y ? db : da;
    float4 v = ((const float4*)src)[i];
    ushort4 o;
    o.x = f2bf(v.x); o.y = f2bf(v.y); o.z = f2bf(v.z); o.w = f2bf(v.w);
    ((ushort4*)dst)[i] = o;
}

// Wt[z][n][k] = W_z[k][n], cast to bf16. block (32,8), grid (32,32,3)
__global__ __launch_bounds__(256) void transpose_cast(const float* __restrict__ Wq,
                                                      const float* __restrict__ Wk,
                                                      const float* __restrict__ Wv,
                                                      ushort_t* __restrict__ Wt) {
    __shared__ float tile[32][33];
    int z = blockIdx.z;
    const float* src = (z == 0) ? Wq : (z == 1 ? Wk : Wv);
    ushort_t* dst = Wt + (size_t)z * W_ * W_;
    int tx = threadIdx.x, ty = threadIdx.y;
    int x = blockIdx.x * 32 + tx;
#pragma unroll
    for (int jj = 0; jj < 4; jj++) {
        int y = blockIdx.y * 32 + ty + jj * 8;
        tile[ty + jj * 8][tx] = src[(size_t)y * W_ + x];
    }
    __syncthreads();
    int x2 = blockIdx.y * 32 + tx;
#pragma unroll
    for (int jj = 0; jj < 4; jj++) {
        int y2 = blockIdx.x * 32 + ty + jj * 8;
        dst[(size_t)y2 * W_ + x2] = f2bf(tile[tx][ty + jj * 8]);
    }
}

// C = A[M,K] x Bt[N,K]^T + bias. M=8192,N=1024,K=1024. 128x128 tile, BK=32.
// grid (512, 3): XCD remap (FETCH 170->53MB proven R3/R4). m97-style loop.
// T2 swizzle (proven R5): LDS slot (row,seg) holds global seg^((row>>1)&3);
// frag read seg qd^((ln>>1)&3) composes to identity. Conflicts -> 0.
// z: 0=Q (scaled 0.125*log2e, [B,H,S,D]) 1=K ([B,H,S,D]) 2=V ([B,H,D,S])
__global__ __launch_bounds__(256) void qkv_gemm(const ushort_t* __restrict__ fromB,
                                                const ushort_t* __restrict__ toB,
                                                const ushort_t* __restrict__ Wt,
                                                const float* __restrict__ bq,
                                                const float* __restrict__ bk,
                                                const float* __restrict__ bv,
                                                ushort_t* __restrict__ Qd,
                                                ushort_t* __restrict__ Kd,
                                                ushort_t* __restrict__ Vt) {
    __shared__ __attribute__((aligned(16))) ushort_t As[128 * 32];
    __shared__ __attribute__((aligned(16))) ushort_t Bs[128 * 32];
    int z = blockIdx.y;
    const ushort_t* A = (z == 0) ? fromB : toB;
    const ushort_t* Bt = Wt + (size_t)z * (W_ * W_);
    const float* bias = (z == 0) ? bq : (z == 1 ? bk : bv);
    ushort_t* dst = (z == 0) ? Qd : (z == 1 ? Kd : Vt);

    // XCD-aware remap (512 blocks/z = 64 per XCD; dispatch round-robin xcd=bx&7)
    int bx = blockIdx.x;
    int j64 = bx >> 3;
    int mTile = ((bx & 7) << 3) | (j64 >> 3);  // 8 M-tiles per XCD
    int nTile = j64 & 7;                        // N fastest within XCD
    int mBase = mTile * 128, nBase = nTile * 128;

    int t = threadIdx.x;
    int lane = t & 63, w = t >> 6;
    int wm = w >> 1, wn = w & 1;
    int ln = lane & 15, qd = lane >> 4;
    int wb = t & ~63;
    int sG = ((t & 3) ^ ((t >> 3) & 3)) << 3;        // swizzled global seg (stage)
    int fs = (qd ^ ((ln >> 1) & 3)) << 3;            // swizzled frag seg (read)

    f32x4 zero = {0.f, 0.f, 0.f, 0.f};
    f32x4 acc[4][4];
#pragma unroll
    for (int i = 0; i < 4; i++)
#pragma unroll
        for (int j = 0; j < 4; j++) acc[i][j] = zero;

    for (int kt = 0; kt < 32; ++kt) {
        int k0 = kt * 32;
#pragma unroll
        for (int c = 0; c < 2; ++c) {
            int idx16 = c * 256 + t;
            int row = idx16 >> 2;
            async16(A + (size_t)(mBase + row) * W_ + k0 + sG, As + (size_t)(c * 256 + wb) * 8);
            async16(Bt + (size_t)(nBase + row) * W_ + k0 + sG, Bs + (size_t)(c * 256 + wb) * 8);
        }
        __syncthreads();
        bf16x8 af[4], bfr[4];
#pragma unroll
        for (int i = 0; i < 4; i++) af[i] = *(const bf16x8*)(As + (wm * 64 + i * 16 + ln) * 32 + fs);
#pragma unroll
        for (int j = 0; j < 4; j++) bfr[j] = *(const bf16x8*)(Bs + (wn * 64 + j * 16 + ln) * 32 + fs);
#pragma unroll
        for (int i = 0; i < 4; i++)
#pragma unroll
            for (int j = 0; j < 4; j++) acc[i][j] = MFMA16(af[i], bfr[j], acc[i][j]);
        __syncthreads();
    }

#pragma unroll
    for (int j = 0; j < 4; j++) {
        int n = nBase + wn * 64 + j * 16 + ln;
        float bb = bias[n];
        int h = n >> 6, d = n & 63;
#pragma unroll
        for (int i = 0; i < 4; i++) {
            int mrow = mBase + wm * 64 + i * 16 + qd * 4;
#pragma unroll
            for (int r = 0; r < 4; r++) {
                int m = mrow + r;
                int b = m >> 10, s = m & 1023;
                float v = acc[i][j][r] + bb;
                if (z == 0) v *= 0.18033688011111773f;  // (1/8)*log2(e): softmax exp2 fold
                size_t idx;
                if (z < 2) idx = ((size_t)(b * H_ + h) * S_ + s) * D_ + d;
                else       idx = ((size_t)(b * H_ + h) * D_ + d) * S_ + s;
                dst[idx] = f2bf(v);
            }
        }
    }
}

// Flash attention v2. grid (S/128, B*H), block 256 (4 waves x 32 queries).
// Q,K: [B,H,S,D] bf16 (Q pre-scaled by 0.125*log2e); V: [B,H,D,S] bf16.
// Swapped QK^T: sc[i][j] = K_tile x Q_tile^T -> lane (ln,qd) holds
// P[key=j*16+qd*4+r][q=i*16+ln] (4 consecutive keys per reg) -> P-store is
// one b64 per (i,j) into Plds[q][key] (contiguous keys), read back as R4's
// proven b128 A-frags. Row sum: scalar rs[i] per lane (16 keys/chunk),
// reduced over qd lanes at the end.
__global__ __launch_bounds__(256, 3) void attn(const ushort_t* __restrict__ Qd,
                                               const ushort_t* __restrict__ Kd,
                                               const ushort_t* __restrict__ Vt,
                                               float* __restrict__ out) {
    __shared__ __attribute__((aligned(16))) ushort_t Ks[2][4096];   // [buf][64 keys x 64 d]
    __shared__ __attribute__((aligned(16))) ushort_t Vs[2][4096];   // [buf][64 d x 64 keys]
    __shared__ __attribute__((aligned(16))) ushort_t Plds[4][32][72];

    int bh = blockIdx.y;
    int t = threadIdx.x, w = t >> 6, lane = t & 63;
    int ln = lane & 15, qd = lane >> 4;
    int qbase = blockIdx.x * 128 + w * 32;
    const ushort_t* Qb = Qd + (size_t)bh * S_ * D_;
    const ushort_t* Kb = Kd + (size_t)bh * S_ * D_;
    const ushort_t* Vb = Vt + (size_t)bh * D_ * S_;

    // Q frags: lane ln holds row (q), qd*8 d-offset. Used as the B operand in
    // swapped QK^T (A/B frag lane maps coincide: row/col<->ln, k<->qd*8+j).
    bf16x8 qf[2][2];
#pragma unroll
    for (int i = 0; i < 2; i++) {
        const ushort_t* qp = Qb + (size_t)(qbase + i * 16 + ln) * D_ + qd * 8;
        qf[i][0] = *(const bf16x8*)qp;
        qf[i][1] = *(const bf16x8*)(qp + 32);
    }

    // staging per-lane constants (8 rows x 64 elem per 1KB async16 block)
    int l8 = lane >> 3, s8 = lane & 7;
    int stgOff = (s8 ^ l8) << 3;  // swizzled 8-elem segment
    const ushort_t* kg = Kb + (size_t)(w * 16 + l8) * D_ + stgOff;
    const ushort_t* vg = Vb + (size_t)(w * 16 + l8) * S_ + stgOff;
    // frag-read per-lane constant: row ln (mod 16), seg qd swizzled by row&7
    int kOff = ln * 64 + ((qd ^ (ln & 7)) << 3);

    float rs[2] = {0.f, 0.f};
    f32x4 zero = {0.f, 0.f, 0.f, 0.f};
    f32x4 accO[2][4];
#pragma unroll
    for (int i = 0; i < 2; i++)
#pragma unroll
        for (int jd = 0; jd < 4; jd++) accO[i][jd] = zero;

    // preload chunk 0 into buf 0 (4 async16 per wave: 2 K-blocks + 2 V-blocks)
    async16(kg, &Ks[0][w * 1024]);
    async16(kg + 8 * D_, &Ks[0][w * 1024 + 512]);
    async16(vg, &Vs[0][w * 1024]);
    async16(vg + 8 * S_, &Vs[0][w * 1024 + 512]);

    for (int c = 0; c < 16; ++c) {
        int buf = c & 1;
        __builtin_amdgcn_s_waitcnt(0x0F70);  // vmcnt(0): chunk c staged
        __syncthreads();                     // all waves: staged + done reading buf^1
        if (c + 1 < 16) {                    // prefetch c+1; lands during compute(c)
            int kc = (c + 1) * 64;
            async16(kg + (size_t)kc * D_, &Ks[buf ^ 1][w * 1024]);
            async16(kg + (size_t)kc * D_ + 8 * D_, &Ks[buf ^ 1][w * 1024 + 512]);
            async16(vg + kc, &Vs[buf ^ 1][w * 1024]);
            async16(vg + kc + 8 * S_, &Vs[buf ^ 1][w * 1024 + 512]);
        }

        // S^T = K Q^T (swapped): sc[i][j][r] = P[key=j*16+qd*4+r][q=i*16+ln]
        f32x4 sc[2][4];
#pragma unroll
        for (int i = 0; i < 2; i++)
#pragma unroll
            for (int j = 0; j < 4; j++) sc[i][j] = zero;
        __builtin_amdgcn_s_setprio(1);
#pragma unroll
        for (int j = 0; j < 4; j++) {
            bf16x8 k0 = *(const bf16x8*)&Ks[buf][j * 1024 + kOff];
            bf16x8 k1 = *(const bf16x8*)&Ks[buf][(j * 1024 + kOff) ^ 32];
#pragma unroll
            for (int i = 0; i < 2; i++) {
                sc[i][j] = MFMA16(k0, qf[i][0], sc[i][j]);
                sc[i][j] = MFMA16(k1, qf[i][1], sc[i][j]);
            }
        }
        __builtin_amdgcn_s_setprio(0);
        // p = exp2(score); rs[i] += 16-key partial sum; pack 4 consecutive
        // keys into one b64 at Plds[q=i*16+ln][key=j*16+qd*4]
#pragma unroll
        for (int i = 0; i < 2; i++)
#pragma unroll
            for (int j = 0; j < 4; j++) {
                float p0 = exp2f(sc[i][j][0]);
                float p1 = exp2f(sc[i][j][1]);
                float p2 = exp2f(sc[i][j][2]);
                float p3 = exp2f(sc[i][j][3]);
                rs[i] += (p0 + p1) + (p2 + p3);
                uint2 pk;
                pk.x = f2bf_rhu_u(p0) | (f2bf_rhu_u(p1) << 16);
                pk.y = f2bf_rhu_u(p2) | (f2bf_rhu_u(p3) << 16);
                *(uint2*)&Plds[w][i * 16 + ln][j * 16 + qd * 4] = pk;
            }
        // same-wave DS order (write->read, R4-proven); fence stops reorder
        asm volatile("" ::: "memory");
        bf16x8 pf[2][2];
#pragma unroll
        for (int i = 0; i < 2; i++) {
            pf[i][0] = *(const bf16x8*)&Plds[w][i * 16 + ln][qd * 8];
            pf[i][1] = *(const bf16x8*)&Plds[w][i * 16 + ln][32 + qd * 8];
        }
        // O += P V
        __builtin_amdgcn_s_setprio(1);
#pragma unroll
        for (int jd = 0; jd < 4; jd++) {
            bf16x8 v0 = *(const bf16x8*)&Vs[buf][jd * 1024 + kOff];
            bf16x8 v1 = *(const bf16x8*)&Vs[buf][(jd * 1024 + kOff) ^ 32];
#pragma unroll
            for (int i = 0; i < 2; i++) {
                accO[i][jd] = MFMA16(pf[i][0], v0, accO[i][jd]);
                accO[i][jd] = MFMA16(pf[i][1], v1, accO[i][jd]);
            }
        }
        __builtin_amdgcn_s_setprio(0);
    }

    // denominators: rs[i] holds this lane's 16-key-per-chunk partials for
    // q=i*16+ln; full sum = reduce over the 4 qd lanes (bits 4,5).
    float inv[2];
#pragma unroll
    for (int i = 0; i < 2; i++) {
        float s = rs[i];
        s += __shfl_xor(s, 16);
        s += __shfl_xor(s, 32);
        inv[i] = 1.f / s;  // valid for q = i*16+ln on every lane
    }
    int b = bh >> 4, h = bh & 15;
#pragma unroll
    for (int i = 0; i < 2; i++)
#pragma unroll
        for (int r = 0; r < 4; r++) {
            // output row q = i*16 + qd*4 + r needs inv computed on lane ln==qd*4+r
            float iv = __shfl(inv[i], qd * 4 + r);
            int q = qbase + i * 16 + qd * 4 + r;
            float* op = out + ((size_t)(b * S_ + q) * H_ + h) * D_;
#pragma unroll
            for (int jd = 0; jd < 4; jd++) op[jd * 16 + ln] = accO[i][jd][r] * iv;
        }
}

extern "C" void kernel_launch(void* const* d_in, const int* in_sizes, int n_in,
                              void* d_out, int out_size, void* d_ws, size_t ws_size,
                              hipStream_t stream) {
    const float* from = (const float*)d_in[0];
    const float* to_  = (const float*)d_in[1];
    const float* Wq = (const float*)d_in[2];
    const float* bq = (const float*)d_in[3];
    const float* Wk = (const float*)d_in[4];
    const float* bk = (const float*)d_in[5];
    const float* Wv = (const float*)d_in[6];
    const float* bv = (const float*)d_in[7];
    float* out = (float*)d_out;

    const size_t NTOK = (size_t)B_ * S_ * W_;  // 8388608
    ushort_t* ws = (ushort_t*)d_ws;
    ushort_t* fromB = ws;
    ushort_t* toB = fromB + NTOK;
    ushort_t* Wt = toB + NTOK;
    ushort_t* Qd = Wt + (size_t)3 * W_ * W_;
    ushort_t* Kd = Qd + NTOK;
    ushort_t* Vt = Kd + NTOK;

    int n4 = (int)(NTOK / 4);
    cast2_bf16<<<dim3(n4 / 256, 2), dim3(256), 0, stream>>>(from, to_, fromB, toB, n4);
    transpose_cast<<<dim3(32, 32, 3), dim3(32, 8), 0, stream>>>(Wq, Wk, Wv, Wt);
    qkv_gemm<<<dim3(512, 3), dim3(256), 0, stream>>>(fromB, toB, Wt, bq, bk, bv, Qd, Kd, Vt);
    attn<<<dim3(8, 128), dim3(256), 0, stream>>>(Qd, Kd, Vt, out);
}

// Round 6
// 270.295 us; speedup vs baseline: 1.1430x; 1.0100x over previous
//
#include <hip/hip_runtime.h>
#include <hip/hip_bf16.h>
#include <math.h>

// Attention_29953101922931: B=8,S=1024,H=16,D=64,W=1024
// R8: qkv reverted to R4-exact (A/B proven: swizzle variant +10.9us, WRITE
//     86->56MB without it; conflicts 6.29M are FREE at this 2-phase structure).
//     attn: P-path LDS roundtrip ELIMINATED — swapped QK^T leaves P[key][q]
//     in registers; PV computed as O^T = V^T P^T with P^T packed in-register
//     as the B-frag (bf16x8 e<->k=qd*8+e, R7-validated). Key->k-slot bijection
//     chosen to match sc regs; Vt global layout stores the same within-64 key
//     permutation (k' = (s&0x23)|((s&0x0C)<<1)|((s&0x10)>>2), r-bits kept ->
//     same epilogue coalescing). DS ops/chunk/wave: 20 -> 8; Plds (18KB) gone;
//     O^T epilogue = contiguous float4 stores; inv needs no redistribution.

#define B_ 8
#define S_ 1024
#define H_ 16
#define D_ 64
#define W_ 1024

typedef __bf16 bf16x8 __attribute__((ext_vector_type(8)));
typedef float f32x4 __attribute__((ext_vector_type(4)));
typedef unsigned short ushort_t;

#define MFMA16(a, b, c) __builtin_amdgcn_mfma_f32_16x16x32_bf16((a), (b), (c), 0, 0, 0)

__device__ inline ushort_t f2bf(float f) {  // RTNE fp32->bf16
    unsigned int u = __float_as_uint(f);
    u += 0x7fff + ((u >> 16) & 1);
    return (ushort_t)(u >> 16);
}

__device__ inline unsigned f2bf_rhu_u(float f) {  // round-half-up bf16 bits (p>=0)
    return (__float_as_uint(f) + 0x8000u) >> 16;
}

__device__ inline void async16(const void* g, void* l) {
    __builtin_amdgcn_global_load_lds((const __attribute__((address_space(1))) void*)g,
                                     (__attribute__((address_space(3))) void*)l, 16, 0, 0);
}

// Both input casts in one dispatch: grid (n4/256, 2)
__global__ __launch_bounds__(256) void cast2_bf16(const float* __restrict__ a,
                                                  const float* __restrict__ b,
                                                  ushort_t* __restrict__ da,
                                                  ushort_t* __restrict__ db, int n4) {
    int i = blockIdx.x * 256 + threadIdx.x;
    if (i >= n4) return;
    const float* src = blockIdx.y ? b : a;
    ushort_t* dst = blockIdx.y ? db : da;
    float4 v = ((const float4*)src)[i];
    ushort4 o;
    o.x = f2bf(v.x); o.y = f2bf(v.y); o.z = f2bf(v.z); o.w = f2bf(v.w);
    ((ushort4*)dst)[i] = o;
}

// Wt[z][n][k] = W_z[k][n], cast to bf16. block (32,8), grid (32,32,3)
__global__ __launch_bounds__(256) void transpose_cast(const float* __restrict__ Wq,
                                                      const float* __restrict__ Wk,
                                                      const float* __restrict__ Wv,
                                                      ushort_t* __restrict__ Wt) {
    __shared__ float tile[32][33];
    int z = blockIdx.z;
    const float* src = (z == 0) ? Wq : (z == 1 ? Wk : Wv);
    ushort_t* dst = Wt + (size_t)z * W_ * W_;
    int tx = threadIdx.x, ty = threadIdx.y;
    int x = blockIdx.x * 32 + tx;
#pragma unroll
    for (int jj = 0; jj < 4; jj++) {
        int y = blockIdx.y * 32 + ty + jj * 8;
        tile[ty + jj * 8][tx] = src[(size_t)y * W_ + x];
    }
    __syncthreads();
    int x2 = blockIdx.y * 32 + tx;
#pragma unroll
    for (int jj = 0; jj < 4; jj++) {
        int y2 = blockIdx.x * 32 + ty + jj * 8;
        dst[(size_t)y2 * W_ + x2] = f2bf(tile[tx][ty + jj * 8]);
    }
}

// C = A[M,K] x Bt[N,K]^T + bias. M=8192,N=1024,K=1024. 128x128 tile, BK=32.
// grid (512, 3): XCD remap (FETCH 170->53MB proven). m97-style 2-barrier loop
// (R4-exact; the seg-swizzle variant measured SLOWER — see R7 post-mortem).
// z: 0=Q (scaled 0.125*log2e, [B,H,S,D]) 1=K ([B,H,S,D])
// 2=V ([B,H,D,S] with within-64 key-bit permutation for attn's in-reg PV)
__global__ __launch_bounds__(256) void qkv_gemm(const ushort_t* __restrict__ fromB,
                                                const ushort_t* __restrict__ toB,
                                                const ushort_t* __restrict__ Wt,
                                                const float* __restrict__ bq,
                                                const float* __restrict__ bk,
                                                const float* __restrict__ bv,
                                                ushort_t* __restrict__ Qd,
                                                ushort_t* __restrict__ Kd,
                                                ushort_t* __restrict__ Vt) {
    __shared__ __attribute__((aligned(16))) ushort_t As[128 * 32];
    __shared__ __attribute__((aligned(16))) ushort_t Bs[128 * 32];
    int z = blockIdx.y;
    const ushort_t* A = (z == 0) ? fromB : toB;
    const ushort_t* Bt = Wt + (size_t)z * (W_ * W_);
    const float* bias = (z == 0) ? bq : (z == 1 ? bk : bv);
    ushort_t* dst = (z == 0) ? Qd : (z == 1 ? Kd : Vt);

    // XCD-aware remap (512 blocks/z = 64 per XCD; dispatch round-robin xcd=bx&7)
    int bx = blockIdx.x;
    int j64 = bx >> 3;
    int mTile = ((bx & 7) << 3) | (j64 >> 3);  // 8 M-tiles per XCD
    int nTile = j64 & 7;                        // N fastest within XCD
    int mBase = mTile * 128, nBase = nTile * 128;

    int t = threadIdx.x;
    int lane = t & 63, w = t >> 6;
    int wm = w >> 1, wn = w & 1;
    int ln = lane & 15, qd = lane >> 4;
    int wb = t & ~63;

    f32x4 zero = {0.f, 0.f, 0.f, 0.f};
    f32x4 acc[4][4];
#pragma unroll
    for (int i = 0; i < 4; i++)
#pragma unroll
        for (int j = 0; j < 4; j++) acc[i][j] = zero;

    for (int kt = 0; kt < 32; ++kt) {
        int k0 = kt * 32;
#pragma unroll
        for (int c = 0; c < 2; ++c) {
            int idx16 = c * 256 + t;
            int row = idx16 >> 2, seg = idx16 & 3;
            async16(A + (size_t)(mBase + row) * W_ + k0 + seg * 8, As + (size_t)(c * 256 + wb) * 8);
            async16(Bt + (size_t)(nBase + row) * W_ + k0 + seg * 8, Bs + (size_t)(c * 256 + wb) * 8);
        }
        __syncthreads();
        bf16x8 af[4], bfr[4];
#pragma unroll
        for (int i = 0; i < 4; i++) af[i] = *(const bf16x8*)(As + (wm * 64 + i * 16 + ln) * 32 + qd * 8);
#pragma unroll
        for (int j = 0; j < 4; j++) bfr[j] = *(const bf16x8*)(Bs + (wn * 64 + j * 16 + ln) * 32 + qd * 8);
#pragma unroll
        for (int i = 0; i < 4; i++)
#pragma unroll
            for (int j = 0; j < 4; j++) acc[i][j] = MFMA16(af[i], bfr[j], acc[i][j]);
        __syncthreads();
    }

#pragma unroll
    for (int j = 0; j < 4; j++) {
        int n = nBase + wn * 64 + j * 16 + ln;
        float bb = bias[n];
        int h = n >> 6, d = n & 63;
#pragma unroll
        for (int i = 0; i < 4; i++) {
            int mrow = mBase + wm * 64 + i * 16 + qd * 4;
#pragma unroll
            for (int r = 0; r < 4; r++) {
                int m = mrow + r;
                int b = m >> 10, s = m & 1023;
                float v = acc[i][j][r] + bb;
                if (z == 0) v *= 0.18033688011111773f;  // (1/8)*log2(e): softmax exp2 fold
                size_t idx;
                if (z < 2) idx = ((size_t)(b * H_ + h) * S_ + s) * D_ + d;
                else {
                    // key-bit permutation within each 64-key group: position
                    // k' holds key (b5=m,b4=jh,b3b2=qd,b1b0=r) at
                    // k' = m*32 + qd*8 + jh*4 + r  (r-bits kept -> coalescing same)
                    int sp = (s & ~63) | (s & 0x23) | ((s & 0x0C) << 1) | ((s & 0x10) >> 2);
                    idx = ((size_t)(b * H_ + h) * D_ + d) * S_ + sp;
                }
                dst[idx] = f2bf(v);
            }
        }
    }
}

// Flash attention v2. grid (S/128, B*H), block 256 (4 waves x 32 queries).
// Q,K: [B,H,S,D] bf16 (Q pre-scaled by 0.125*log2e); V: [B,H,D,S] key-permuted.
// Swapped QK^T: sc[i][j][r] = P[key=j*16+qd*4+r][q=i*16+ln]. Softmax + P->bf16
// fully in-register; PV as O^T = V^T P^T with pfrag as B operand (element e of
// mfma m = P[key 32m+16*(e>>2)+4qd+(e&3)]) and V A-frags read b128 from Vs
// (Vt pre-permuted so those keys are contiguous at position 32m+8qd+e).
// accO[i][dt] = O^T[d=dt*16+qd*4+rr][q=i*16+ln] -> float4 stores.
__global__ __launch_bounds__(256, 3) void attn(const ushort_t* __restrict__ Qd,
                                               const ushort_t* __restrict__ Kd,
                                               const ushort_t* __restrict__ Vt,
                                               float* __restrict__ out) {
    __shared__ __attribute__((aligned(16))) ushort_t Ks[2][4096];   // [buf][64 keys x 64 d]
    __shared__ __attribute__((aligned(16))) ushort_t Vs[2][4096];   // [buf][64 d x 64 perm-keys]

    int bh = blockIdx.y;
    int t = threadIdx.x, w = t >> 6, lane = t & 63;
    int ln = lane & 15, qd = lane >> 4;
    int qbase = blockIdx.x * 128 + w * 32;
    const ushort_t* Qb = Qd + (size_t)bh * S_ * D_;
    const ushort_t* Kb = Kd + (size_t)bh * S_ * D_;
    const ushort_t* Vb = Vt + (size_t)bh * D_ * S_;

    // Q frags: lane ln holds row (q), qd*8 d-offset (B operand of swapped QK^T)
    bf16x8 qf[2][2];
#pragma unroll
    for (int i = 0; i < 2; i++) {
        const ushort_t* qp = Qb + (size_t)(qbase + i * 16 + ln) * D_ + qd * 8;
        qf[i][0] = *(const bf16x8*)qp;
        qf[i][1] = *(const bf16x8*)(qp + 32);
    }

    // staging per-lane constants (8 rows x 64 elem per 1KB async16 block)
    int l8 = lane >> 3, s8 = lane & 7;
    int stgOff = (s8 ^ l8) << 3;  // swizzled 8-elem segment
    const ushort_t* kg = Kb + (size_t)(w * 16 + l8) * D_ + stgOff;
    const ushort_t* vg = Vb + (size_t)(w * 16 + l8) * S_ + stgOff;
    // K frag-read: row ln (mod 16), seg qd swizzled by row&7
    int kOff = ln * 64 + ((qd ^ (ln & 7)) << 3);

    float rs[2] = {0.f, 0.f};
    f32x4 zero = {0.f, 0.f, 0.f, 0.f};
    f32x4 accO[2][4];
#pragma unroll
    for (int i = 0; i < 2; i++)
#pragma unroll
        for (int jd = 0; jd < 4; jd++) accO[i][jd] = zero;

    // preload chunk 0 into buf 0 (4 async16 per wave: 2 K-blocks + 2 V-blocks)
    async16(kg, &Ks[0][w * 1024]);
    async16(kg + 8 * D_, &Ks[0][w * 1024 + 512]);
    async16(vg, &Vs[0][w * 1024]);
    async16(vg + 8 * S_, &Vs[0][w * 1024 + 512]);

    for (int c = 0; c < 16; ++c) {
        int buf = c & 1;
        __builtin_amdgcn_s_waitcnt(0x0F70);  // vmcnt(0): chunk c staged
        __syncthreads();                     // all waves: staged + done reading buf^1
        if (c + 1 < 16) {                    // prefetch c+1; lands during compute(c)
            int kc = (c + 1) * 64;
            async16(kg + (size_t)kc * D_, &Ks[buf ^ 1][w * 1024]);
            async16(kg + (size_t)kc * D_ + 8 * D_, &Ks[buf ^ 1][w * 1024 + 512]);
            async16(vg + kc, &Vs[buf ^ 1][w * 1024]);
            async16(vg + kc + 8 * S_, &Vs[buf ^ 1][w * 1024 + 512]);
        }

        // S^T = K Q^T (swapped): sc[i][j][r] = P[key=j*16+qd*4+r][q=i*16+ln]
        f32x4 sc[2][4];
#pragma unroll
        for (int i = 0; i < 2; i++)
#pragma unroll
            for (int j = 0; j < 4; j++) sc[i][j] = zero;
        __builtin_amdgcn_s_setprio(1);
#pragma unroll
        for (int j = 0; j < 4; j++) {
            bf16x8 k0 = *(const bf16x8*)&Ks[buf][j * 1024 + kOff];
            bf16x8 k1 = *(const bf16x8*)&Ks[buf][(j * 1024 + kOff) ^ 32];
#pragma unroll
            for (int i = 0; i < 2; i++) {
                sc[i][j] = MFMA16(k0, qf[i][0], sc[i][j]);
                sc[i][j] = MFMA16(k1, qf[i][1], sc[i][j]);
            }
        }
        __builtin_amdgcn_s_setprio(0);

        // softmax + P^T B-frags fully in-register: pfrag[i][m] element e holds
        // bf16(exp2(sc[i][2m+(e>>2)][e&3])) = P[key 32m+16jh+4qd+r][q]
        bf16x8 pfrag[2][2];
#pragma unroll
        for (int i = 0; i < 2; i++)
#pragma unroll
            for (int m = 0; m < 2; m++) {
                union { unsigned u[4]; bf16x8 v; } pk;
#pragma unroll
                for (int jh = 0; jh < 2; jh++) {
                    float p0 = exp2f(sc[i][2 * m + jh][0]);
                    float p1 = exp2f(sc[i][2 * m + jh][1]);
                    float p2 = exp2f(sc[i][2 * m + jh][2]);
                    float p3 = exp2f(sc[i][2 * m + jh][3]);
                    rs[i] += (p0 + p1) + (p2 + p3);
                    pk.u[jh * 2]     = f2bf_rhu_u(p0) | (f2bf_rhu_u(p1) << 16);
                    pk.u[jh * 2 + 1] = f2bf_rhu_u(p2) | (f2bf_rhu_u(p3) << 16);
                }
                pfrag[i][m] = pk.v;
            }

        // O^T += V^T P^T (V A-frags: row d=dt*16+ln, perm-key seg (4m+qd)^(d&7))
        __builtin_amdgcn_s_setprio(1);
#pragma unroll
        for (int dt = 0; dt < 4; dt++)
#pragma unroll
            for (int m = 0; m < 2; m++) {
                bf16x8 vf = *(const bf16x8*)&Vs[buf][(dt * 16 + ln) * 64 +
                                                    ((((m << 2) + qd) ^ (ln & 7)) << 3)];
                accO[0][dt] = MFMA16(vf, pfrag[0][m], accO[0][dt]);
                accO[1][dt] = MFMA16(vf, pfrag[1][m], accO[1][dt]);
            }
        __builtin_amdgcn_s_setprio(0);
    }

    // denominators: rs[i] = this lane's partial for q=i*16+ln (16 keys/chunk);
    // full sum over the 4 qd lanes (xor bits 4,5). inv valid on every lane.
    float inv[2];
#pragma unroll
    for (int i = 0; i < 2; i++) {
        float s = rs[i];
        s += __shfl_xor(s, 16);
        s += __shfl_xor(s, 32);
        inv[i] = 1.f / s;
    }
    int b = bh >> 4, h = bh & 15;
#pragma unroll
    for (int i = 0; i < 2; i++) {
        int q = qbase + i * 16 + ln;
        float* op = out + ((size_t)(b * S_ + q) * H_ + h) * D_ + qd * 4;
#pragma unroll
        for (int dt = 0; dt < 4; dt++) {
            float4 o4;
            o4.x = accO[i][dt][0] * inv[i];
            o4.y = accO[i][dt][1] * inv[i];
            o4.z = accO[i][dt][2] * inv[i];
            o4.w = accO[i][dt][3] * inv[i];
            *(float4*)(op + dt * 16) = o4;
        }
    }
}

extern "C" void kernel_launch(void* const* d_in, const int* in_sizes, int n_in,
                              void* d_out, int out_size, void* d_ws, size_t ws_size,
                              hipStream_t stream) {
    const float* from = (const float*)d_in[0];
    const float* to_  = (const float*)d_in[1];
    const float* Wq = (const float*)d_in[2];
    const float* bq = (const float*)d_in[3];
    const float* Wk = (const float*)d_in[4];
    const float* bk = (const float*)d_in[5];
    const float* Wv = (const float*)d_in[6];
    const float* bv = (const float*)d_in[7];
    float* out = (float*)d_out;

    const size_t NTOK = (size_t)B_ * S_ * W_;  // 8388608
    ushort_t* ws = (ushort_t*)d_ws;
    ushort_t* fromB = ws;
    ushort_t* toB = fromB + NTOK;
    ushort_t* Wt = toB + NTOK;
    ushort_t* Qd = Wt + (size_t)3 * W_ * W_;
    ushort_t* Kd = Qd + NTOK;
    ushort_t* Vt = Kd + NTOK;

    int n4 = (int)(NTOK / 4);
    cast2_bf16<<<dim3(n4 / 256, 2), dim3(256), 0, stream>>>(from, to_, fromB, toB, n4);
    transpose_cast<<<dim3(32, 32, 3), dim3(32, 8), 0, stream>>>(Wq, Wk, Wv, Wt);
    qkv_gemm<<<dim3(512, 3), dim3(256), 0, stream>>>(fromB, toB, Wt, bq, bk, bv, Qd, Kd, Vt);
    attn<<<dim3(8, 128), dim3(256), 0, stream>>>(Qd, Kd, Vt, out);
}

// Round 7
// 262.049 us; speedup vs baseline: 1.1790x; 1.0315x over previous
//
#include <hip/hip_runtime.h>
#include <hip/hip_bf16.h>
#include <math.h>

// Attention_29953101922931: B=8,S=1024,H=16,D=64,W=1024
// R9: attn XCD-aware bh grouping — old grid (8,128) put the 8 q-tiles of one
//     bh on 8 DIFFERENT XCDs (XCD = linear_id&7), so each XCD streamed K/V of
//     all 128 bh (32MB) through its 4MB L2 -> ~8x HBM re-fetch (~268MB).
//     Remap: XCD c owns bh [16c,16c+16): bh=((L&7)<<4)|((L>>3)&15), qx=L>>7;
//     per-XCD K/V working set = 4MB = one L2 (same mechanism as qkv's proven
//     FETCH 170->53MB remap). attn occupancy 3->4 blocks/CU (grid 1024 = 256
//     CUs x 4, all resident, no tail; LDS 32KB*4=128<=160KB). cast2+transpose
//     merged into one prep dispatch. qkv unchanged (R4-exact, 88.9us proven).

#define B_ 8
#define S_ 1024
#define H_ 16
#define D_ 64
#define W_ 1024

typedef __bf16 bf16x8 __attribute__((ext_vector_type(8)));
typedef float f32x4 __attribute__((ext_vector_type(4)));
typedef unsigned short ushort_t;

#define MFMA16(a, b, c) __builtin_amdgcn_mfma_f32_16x16x32_bf16((a), (b), (c), 0, 0, 0)

__device__ inline ushort_t f2bf(float f) {  // RTNE fp32->bf16
    unsigned int u = __float_as_uint(f);
    u += 0x7fff + ((u >> 16) & 1);
    return (ushort_t)(u >> 16);
}

__device__ inline unsigned f2bf_rhu_u(float f) {  // round-half-up bf16 bits (p>=0)
    return (__float_as_uint(f) + 0x8000u) >> 16;
}

__device__ inline void async16(const void* g, void* l) {
    __builtin_amdgcn_global_load_lds((const __attribute__((address_space(1))) void*)g,
                                     (__attribute__((address_space(3))) void*)l, 16, 0, 0);
}

// Merged prep: grid (8192, 3). z=0/1: cast from/to -> bf16 (float4 lanes).
// z=2: W transposes (3072 active blocks: matrix zz = bx>>10, tile bx&1023).
__global__ __launch_bounds__(256) void prep(const float* __restrict__ from,
                                            const float* __restrict__ to_,
                                            const float* __restrict__ Wq,
                                            const float* __restrict__ Wk,
                                            const float* __restrict__ Wv,
                                            ushort_t* __restrict__ fromB,
                                            ushort_t* __restrict__ toB,
                                            ushort_t* __restrict__ Wt, int n4) {
    int z = blockIdx.y;
    int t = threadIdx.x;
    if (z < 2) {
        int i = blockIdx.x * 256 + t;
        if (i >= n4) return;
        const float* src = z ? to_ : from;
        ushort_t* dst = z ? toB : fromB;
        float4 v = ((const float4*)src)[i];
        ushort4 o;
        o.x = f2bf(v.x); o.y = f2bf(v.y); o.z = f2bf(v.z); o.w = f2bf(v.w);
        ((ushort4*)dst)[i] = o;
        return;
    }
    int bx = blockIdx.x;
    if (bx >= 3072) return;
    __shared__ float tile[32][33];
    int zz = bx >> 10;
    int tl = bx & 1023;
    int bxx = tl & 31, byy = tl >> 5;
    const float* src = (zz == 0) ? Wq : (zz == 1 ? Wk : Wv);
    ushort_t* dst = Wt + (size_t)zz * W_ * W_;
    int tx = t & 31, ty = t >> 5;  // (32,8)
    int x = bxx * 32 + tx;
#pragma unroll
    for (int jj = 0; jj < 4; jj++) {
        int y = byy * 32 + ty + jj * 8;
        tile[ty + jj * 8][tx] = src[(size_t)y * W_ + x];
    }
    __syncthreads();
    int x2 = byy * 32 + tx;
#pragma unroll
    for (int jj = 0; jj < 4; jj++) {
        int y2 = bxx * 32 + ty + jj * 8;
        dst[(size_t)y2 * W_ + x2] = f2bf(tile[tx][ty + jj * 8]);
    }
}

// C = A[M,K] x Bt[N,K]^T + bias. M=8192,N=1024,K=1024. 128x128 tile, BK=32.
// grid (512, 3): XCD remap (FETCH 170->53MB proven). m97-style 2-barrier loop
// (R4-exact; seg-swizzle variant measured slower, dbuf variant measured slower).
// z: 0=Q (scaled 0.125*log2e, [B,H,S,D]) 1=K ([B,H,S,D])
// 2=V ([B,H,D,S] with within-64 key-bit permutation for attn's in-reg PV)
__global__ __launch_bounds__(256) void qkv_gemm(const ushort_t* __restrict__ fromB,
                                                const ushort_t* __restrict__ toB,
                                                const ushort_t* __restrict__ Wt,
                                                const float* __restrict__ bq,
                                                const float* __restrict__ bk,
                                                const float* __restrict__ bv,
                                                ushort_t* __restrict__ Qd,
                                                ushort_t* __restrict__ Kd,
                                                ushort_t* __restrict__ Vt) {
    __shared__ __attribute__((aligned(16))) ushort_t As[128 * 32];
    __shared__ __attribute__((aligned(16))) ushort_t Bs[128 * 32];
    int z = blockIdx.y;
    const ushort_t* A = (z == 0) ? fromB : toB;
    const ushort_t* Bt = Wt + (size_t)z * (W_ * W_);
    const float* bias = (z == 0) ? bq : (z == 1 ? bk : bv);
    ushort_t* dst = (z == 0) ? Qd : (z == 1 ? Kd : Vt);

    // XCD-aware remap (512 blocks/z = 64 per XCD; dispatch round-robin xcd=bx&7)
    int bx = blockIdx.x;
    int j64 = bx >> 3;
    int mTile = ((bx & 7) << 3) | (j64 >> 3);  // 8 M-tiles per XCD
    int nTile = j64 & 7;                        // N fastest within XCD
    int mBase = mTile * 128, nBase = nTile * 128;

    int t = threadIdx.x;
    int lane = t & 63, w = t >> 6;
    int wm = w >> 1, wn = w & 1;
    int ln = lane & 15, qd = lane >> 4;
    int wb = t & ~63;

    f32x4 zero = {0.f, 0.f, 0.f, 0.f};
    f32x4 acc[4][4];
#pragma unroll
    for (int i = 0; i < 4; i++)
#pragma unroll
        for (int j = 0; j < 4; j++) acc[i][j] = zero;

    for (int kt = 0; kt < 32; ++kt) {
        int k0 = kt * 32;
#pragma unroll
        for (int c = 0; c < 2; ++c) {
            int idx16 = c * 256 + t;
            int row = idx16 >> 2, seg = idx16 & 3;
            async16(A + (size_t)(mBase + row) * W_ + k0 + seg * 8, As + (size_t)(c * 256 + wb) * 8);
            async16(Bt + (size_t)(nBase + row) * W_ + k0 + seg * 8, Bs + (size_t)(c * 256 + wb) * 8);
        }
        __syncthreads();
        bf16x8 af[4], bfr[4];
#pragma unroll
        for (int i = 0; i < 4; i++) af[i] = *(const bf16x8*)(As + (wm * 64 + i * 16 + ln) * 32 + qd * 8);
#pragma unroll
        for (int j = 0; j < 4; j++) bfr[j] = *(const bf16x8*)(Bs + (wn * 64 + j * 16 + ln) * 32 + qd * 8);
#pragma unroll
        for (int i = 0; i < 4; i++)
#pragma unroll
            for (int j = 0; j < 4; j++) acc[i][j] = MFMA16(af[i], bfr[j], acc[i][j]);
        __syncthreads();
    }

#pragma unroll
    for (int j = 0; j < 4; j++) {
        int n = nBase + wn * 64 + j * 16 + ln;
        float bb = bias[n];
        int h = n >> 6, d = n & 63;
#pragma unroll
        for (int i = 0; i < 4; i++) {
            int mrow = mBase + wm * 64 + i * 16 + qd * 4;
#pragma unroll
            for (int r = 0; r < 4; r++) {
                int m = mrow + r;
                int b = m >> 10, s = m & 1023;
                float v = acc[i][j][r] + bb;
                if (z == 0) v *= 0.18033688011111773f;  // (1/8)*log2(e): softmax exp2 fold
                size_t idx;
                if (z < 2) idx = ((size_t)(b * H_ + h) * S_ + s) * D_ + d;
                else {
                    // key-bit permutation within each 64-key group:
                    // k' = m*32 + qd*8 + jh*4 + r (r-bits kept -> coalescing same)
                    int sp = (s & ~63) | (s & 0x23) | ((s & 0x0C) << 1) | ((s & 0x10) >> 2);
                    idx = ((size_t)(b * H_ + h) * D_ + d) * S_ + sp;
                }
                dst[idx] = f2bf(v);
            }
        }
    }
}

// Flash attention. grid 1024 linear, block 256 (4 waves x 32 queries), 4 blk/CU.
// XCD grouping: bh = ((L&7)<<4)|((L>>3)&15), qx = L>>7 -> XCD c owns bh
// [16c,16c+16) (K/V working set 4MB = one XCD L2).
// Q,K: [B,H,S,D] bf16 (Q pre-scaled by 0.125*log2e); V: [B,H,D,S] key-permuted.
// Swapped QK^T: sc[i][j][r] = P[key=j*16+qd*4+r][q=i*16+ln]; softmax+P->bf16
// in-register (pfrag = PV B-operand); V A-frags b128 from Vs (pre-permuted Vt).
__global__ __launch_bounds__(256, 4) void attn(const ushort_t* __restrict__ Qd,
                                               const ushort_t* __restrict__ Kd,
                                               const ushort_t* __restrict__ Vt,
                                               float* __restrict__ out) {
    __shared__ __attribute__((aligned(16))) ushort_t Ks[2][4096];   // [buf][64 keys x 64 d]
    __shared__ __attribute__((aligned(16))) ushort_t Vs[2][4096];   // [buf][64 d x 64 perm-keys]

    int L = blockIdx.x;
    int bh = ((L & 7) << 4) | ((L >> 3) & 15);
    int qx = L >> 7;
    int t = threadIdx.x, w = t >> 6, lane = t & 63;
    int ln = lane & 15, qd = lane >> 4;
    int qbase = qx * 128 + w * 32;
    const ushort_t* Qb = Qd + (size_t)bh * S_ * D_;
    const ushort_t* Kb = Kd + (size_t)bh * S_ * D_;
    const ushort_t* Vb = Vt + (size_t)bh * D_ * S_;

    // Q frags: lane ln holds row (q), qd*8 d-offset (B operand of swapped QK^T)
    bf16x8 qf[2][2];
#pragma unroll
    for (int i = 0; i < 2; i++) {
        const ushort_t* qp = Qb + (size_t)(qbase + i * 16 + ln) * D_ + qd * 8;
        qf[i][0] = *(const bf16x8*)qp;
        qf[i][1] = *(const bf16x8*)(qp + 32);
    }

    // staging per-lane constants (8 rows x 64 elem per 1KB async16 block)
    int l8 = lane >> 3, s8 = lane & 7;
    int stgOff = (s8 ^ l8) << 3;  // swizzled 8-elem segment
    const ushort_t* kg = Kb + (size_t)(w * 16 + l8) * D_ + stgOff;
    const ushort_t* vg = Vb + (size_t)(w * 16 + l8) * S_ + stgOff;
    // K frag-read: row ln (mod 16), seg qd swizzled by row&7
    int kOff = ln * 64 + ((qd ^ (ln & 7)) << 3);

    float rs[2] = {0.f, 0.f};
    f32x4 zero = {0.f, 0.f, 0.f, 0.f};
    f32x4 accO[2][4];
#pragma unroll
    for (int i = 0; i < 2; i++)
#pragma unroll
        for (int jd = 0; jd < 4; jd++) accO[i][jd] = zero;

    // preload chunk 0 into buf 0 (4 async16 per wave: 2 K-blocks + 2 V-blocks)
    async16(kg, &Ks[0][w * 1024]);
    async16(kg + 8 * D_, &Ks[0][w * 1024 + 512]);
    async16(vg, &Vs[0][w * 1024]);
    async16(vg + 8 * S_, &Vs[0][w * 1024 + 512]);

    for (int c = 0; c < 16; ++c) {
        int buf = c & 1;
        __builtin_amdgcn_s_waitcnt(0x0F70);  // vmcnt(0): chunk c staged
        __syncthreads();                     // all waves: staged + done reading buf^1
        if (c + 1 < 16) {                    // prefetch c+1; lands during compute(c)
            int kc = (c + 1) * 64;
            async16(kg + (size_t)kc * D_, &Ks[buf ^ 1][w * 1024]);
            async16(kg + (size_t)kc * D_ + 8 * D_, &Ks[buf ^ 1][w * 1024 + 512]);
            async16(vg + kc, &Vs[buf ^ 1][w * 1024]);
            async16(vg + kc + 8 * S_, &Vs[buf ^ 1][w * 1024 + 512]);
        }

        // S^T = K Q^T (swapped): sc[i][j][r] = P[key=j*16+qd*4+r][q=i*16+ln]
        f32x4 sc[2][4];
#pragma unroll
        for (int i = 0; i < 2; i++)
#pragma unroll
            for (int j = 0; j < 4; j++) sc[i][j] = zero;
        __builtin_amdgcn_s_setprio(1);
#pragma unroll
        for (int j = 0; j < 4; j++) {
            bf16x8 k0 = *(const bf16x8*)&Ks[buf][j * 1024 + kOff];
            bf16x8 k1 = *(const bf16x8*)&Ks[buf][(j * 1024 + kOff) ^ 32];
#pragma unroll
            for (int i = 0; i < 2; i++) {
                sc[i][j] = MFMA16(k0, qf[i][0], sc[i][j]);
                sc[i][j] = MFMA16(k1, qf[i][1], sc[i][j]);
            }
        }
        __builtin_amdgcn_s_setprio(0);

        // softmax + P^T B-frags in-register: pfrag[i][m] element e holds
        // bf16(exp2(sc[i][2m+(e>>2)][e&3])) = P[key 32m+16jh+4qd+r][q]
        bf16x8 pfrag[2][2];
#pragma unroll
        for (int i = 0; i < 2; i++)
#pragma unroll
            for (int m = 0; m < 2; m++) {
                union { unsigned u[4]; bf16x8 v; } pk;
#pragma unroll
                for (int jh = 0; jh < 2; jh++) {
                    float p0 = exp2f(sc[i][2 * m + jh][0]);
                    float p1 = exp2f(sc[i][2 * m + jh][1]);
                    float p2 = exp2f(sc[i][2 * m + jh][2]);
                    float p3 = exp2f(sc[i][2 * m + jh][3]);
                    rs[i] += (p0 + p1) + (p2 + p3);
                    pk.u[jh * 2]     = f2bf_rhu_u(p0) | (f2bf_rhu_u(p1) << 16);
                    pk.u[jh * 2 + 1] = f2bf_rhu_u(p2) | (f2bf_rhu_u(p3) << 16);
                }
                pfrag[i][m] = pk.v;
            }

        // O^T += V^T P^T (V A-frags: row d=dt*16+ln, perm-key seg (4m+qd)^(d&7))
        __builtin_amdgcn_s_setprio(1);
#pragma unroll
        for (int dt = 0; dt < 4; dt++)
#pragma unroll
            for (int m = 0; m < 2; m++) {
                bf16x8 vf = *(const bf16x8*)&Vs[buf][(dt * 16 + ln) * 64 +
                                                    ((((m << 2) + qd) ^ (ln & 7)) << 3)];
                accO[0][dt] = MFMA16(vf, pfrag[0][m], accO[0][dt]);
                accO[1][dt] = MFMA16(vf, pfrag[1][m], accO[1][dt]);
            }
        __builtin_amdgcn_s_setprio(0);
    }

    // denominators: rs[i] = this lane's partial for q=i*16+ln (16 keys/chunk);
    // full sum over the 4 qd lanes (xor bits 4,5). inv valid on every lane.
    float inv[2];
#pragma unroll
    for (int i = 0; i < 2; i++) {
        float s = rs[i];
        s += __shfl_xor(s, 16);
        s += __shfl_xor(s, 32);
        inv[i] = 1.f / s;
    }
    int b = bh >> 4, h = bh & 15;
#pragma unroll
    for (int i = 0; i < 2; i++) {
        int q = qbase + i * 16 + ln;
        float* op = out + ((size_t)(b * S_ + q) * H_ + h) * D_ + qd * 4;
#pragma unroll
        for (int dt = 0; dt < 4; dt++) {
            float4 o4;
            o4.x = accO[i][dt][0] * inv[i];
            o4.y = accO[i][dt][1] * inv[i];
            o4.z = accO[i][dt][2] * inv[i];
            o4.w = accO[i][dt][3] * inv[i];
            *(float4*)(op + dt * 16) = o4;
        }
    }
}

extern "C" void kernel_launch(void* const* d_in, const int* in_sizes, int n_in,
                              void* d_out, int out_size, void* d_ws, size_t ws_size,
                              hipStream_t stream) {
    const float* from = (const float*)d_in[0];
    const float* to_  = (const float*)d_in[1];
    const float* Wq = (const float*)d_in[2];
    const float* bq = (const float*)d_in[3];
    const float* Wk = (const float*)d_in[4];
    const float* bk = (const float*)d_in[5];
    const float* Wv = (const float*)d_in[6];
    const float* bv = (const float*)d_in[7];
    float* out = (float*)d_out;

    const size_t NTOK = (size_t)B_ * S_ * W_;  // 8388608
    ushort_t* ws = (ushort_t*)d_ws;
    ushort_t* fromB = ws;
    ushort_t* toB = fromB + NTOK;
    ushort_t* Wt = toB + NTOK;
    ushort_t* Qd = Wt + (size_t)3 * W_ * W_;
    ushort_t* Kd = Qd + NTOK;
    ushort_t* Vt = Kd + NTOK;

    int n4 = (int)(NTOK / 4);
    prep<<<dim3(n4 / 256, 3), dim3(256), 0, stream>>>(from, to_, Wq, Wk, Wv, fromB, toB, Wt, n4);
    qkv_gemm<<<dim3(512, 3), dim3(256), 0, stream>>>(fromB, toB, Wt, bq, bk, bv, Qd, Kd, Vt);
    attn<<<dim3(1024), dim3(256), 0, stream>>>(Qd, Kd, Vt, out);
}